// Round 12
// baseline (611.559 us; speedup 1.0000x reference)
//
#include <hip/hip_runtime.h>
#include <math.h>
#include <stdint.h>

#define Nn 4096
#define Ee 1024
#define Dd 256

typedef __attribute__((ext_vector_type(8))) __bf16 bf16x8;
typedef __attribute__((ext_vector_type(4))) float f32x4;
typedef __attribute__((ext_vector_type(8))) unsigned short u16x8;

__device__ __forceinline__ unsigned short f2bf(float f) {
  unsigned int u = __float_as_uint(f);
  unsigned int r = (u + 0x7fffu + ((u >> 16) & 1u)) >> 16;
  return (unsigned short)r;
}
__device__ __forceinline__ float bf2f(unsigned short u) {
  return __uint_as_float(((unsigned int)u) << 16);
}

__device__ __forceinline__ void gload_lds16(const void* g, void* l) {
  __builtin_amdgcn_global_load_lds(
      (__attribute__((address_space(1))) void*)const_cast<void*>(g),
      (__attribute__((address_space(3))) void*)l, 16, 0, 0);
}

__device__ __forceinline__ float block_reduce_sum(float v) {
  __shared__ float sh[4];
  #pragma unroll
  for (int o = 32; o > 0; o >>= 1) v += __shfl_down(v, o);
  int lane = threadIdx.x & 63, w = threadIdx.x >> 6;
  if (lane == 0) sh[w] = v;
  __syncthreads();
  float s = sh[0] + sh[1] + sh[2] + sh[3];
  __syncthreads();
  return s;
}

// ======== device core: 128x128 tile, BK=32, split-K, atomic f32 out ========
__device__ __forceinline__ void bts_dev(
    const unsigned short* __restrict__ Ab, const unsigned short* __restrict__ Bb,
    float* __restrict__ Cp, int N, int lda, int ldb,
    int m0, int n0, int kbase, int NT, unsigned short* SM)
{
  unsigned short* As = SM;          // [2][4096]
  unsigned short* Bs = SM + 8192;   // [2][4096]
  const int tid = threadIdx.x;
  const int wave = tid >> 6, lane = tid & 63;
  const int wr = (wave >> 1) * 64, wc = (wave & 1) * 64;
  const int l16 = lane & 15, lq = lane >> 4;
  f32x4 acc[4][4] = {};

  auto stage = [&](int buf, int kt) {
    const int k0 = kbase + kt * 32;
    #pragma unroll
    for (int i = 0; i < 2; ++i) {
      int t2 = tid + i * 256;
      int r = t2 >> 2, c = (t2 & 3) * 8;
      gload_lds16(Ab + (size_t)(m0 + r) * lda + k0 + c, As + buf * 4096 + t2 * 8);
    }
    #pragma unroll
    for (int i = 0; i < 2; ++i) {
      int t2 = tid + i * 256;
      int r = t2 >> 2, c = (t2 & 3) * 8;
      gload_lds16(Bb + (size_t)(n0 + r) * ldb + k0 + c, Bs + buf * 4096 + t2 * 8);
    }
  };

  stage(0, 0);
  __syncthreads();
  int buf = 0;
  for (int kt = 0; kt < NT; ++kt) {
    if (kt + 1 < NT) stage(buf ^ 1, kt + 1);
    bf16x8 af[4], bfr[4];
    #pragma unroll
    for (int m = 0; m < 4; ++m)
      af[m] = *reinterpret_cast<const bf16x8*>(As + buf * 4096 + (wr + m * 16 + l16) * 32 + lq * 8);
    #pragma unroll
    for (int n = 0; n < 4; ++n)
      bfr[n] = *reinterpret_cast<const bf16x8*>(Bs + buf * 4096 + (wc + n * 16 + l16) * 32 + lq * 8);
    #pragma unroll
    for (int m = 0; m < 4; ++m)
      #pragma unroll
      for (int n = 0; n < 4; ++n)
        acc[m][n] = __builtin_amdgcn_mfma_f32_16x16x32_bf16(af[m], bfr[n], acc[m][n], 0, 0, 0);
    __syncthreads();
    buf ^= 1;
  }
  #pragma unroll
  for (int m = 0; m < 4; ++m)
    #pragma unroll
    for (int n = 0; n < 4; ++n) {
      int col = n0 + wc + n * 16 + l16;
      #pragma unroll
      for (int q = 0; q < 4; ++q) {
        int row = m0 + wr + m * 16 + lq * 4 + q;
        atomicAdd(&Cp[(size_t)row * N + col], acc[m][n][q]);
      }
    }
}

// ======== symmetric gram, BK=64 dbuf (64KB LDS), early-exit (32,32) grid ========
__global__ __launch_bounds__(256) void gram_k(
    const unsigned short* __restrict__ CAT,   // [Nn][2048] bf16
    const unsigned short* __restrict__ Gb,    // bf16 G probs (additive term)
    unsigned short* __restrict__ Gexp,        // out: exp(G + gram)
    float* __restrict__ rowsum)               // pre-zeroed [Nn]
{
  const int bx = blockIdx.x, by = blockIdx.y;
  if (bx > by) return;
  const int K = 2048;
  __shared__ unsigned short SM[32768];        // 64 KB
  unsigned short* Asb = SM;                   // [2][8192]
  unsigned short* Bsb = SM + 16384;
  const int tid = threadIdx.x;
  const int m0 = bx * 128, n0 = by * 128;
  const int wave = tid >> 6, lane = tid & 63;
  const int wr = (wave >> 1) * 64, wc = (wave & 1) * 64;
  const int l16 = lane & 15, lq = lane >> 4;
  f32x4 acc[4][4] = {};
  const int NT = K >> 6;                      // 32

  auto stage = [&](int buf, int kt) {
    const int k0 = kt * 64;
    #pragma unroll
    for (int i = 0; i < 4; ++i) {
      int t2 = tid + i * 256;
      int r = t2 >> 3, c = (t2 & 7) * 8;
      gload_lds16(CAT + (size_t)(m0 + r) * K + k0 + c, Asb + buf * 8192 + t2 * 8);
    }
    #pragma unroll
    for (int i = 0; i < 4; ++i) {
      int t2 = tid + i * 256;
      int r = t2 >> 3, c = (t2 & 7) * 8;
      gload_lds16(CAT + (size_t)(n0 + r) * K + k0 + c, Bsb + buf * 8192 + t2 * 8);
    }
  };

  stage(0, 0);
  __syncthreads();
  int buf = 0;
  for (int kt = 0; kt < NT; ++kt) {
    if (kt + 1 < NT) stage(buf ^ 1, kt + 1);
    #pragma unroll
    for (int ks = 0; ks < 2; ++ks) {
      bf16x8 af[4], bfr[4];
      #pragma unroll
      for (int m = 0; m < 4; ++m)
        af[m] = *reinterpret_cast<const bf16x8*>(
            Asb + buf * 8192 + (wr + m * 16 + l16) * 64 + ks * 32 + lq * 8);
      #pragma unroll
      for (int n = 0; n < 4; ++n)
        bfr[n] = *reinterpret_cast<const bf16x8*>(
            Bsb + buf * 8192 + (wc + n * 16 + l16) * 64 + ks * 32 + lq * 8);
      #pragma unroll
      for (int m = 0; m < 4; ++m)
        #pragma unroll
        for (int n = 0; n < 4; ++n)
          acc[m][n] = __builtin_amdgcn_mfma_f32_16x16x32_bf16(af[m], bfr[n], acc[m][n], 0, 0, 0);
    }
    __syncthreads();
    buf ^= 1;
  }
  // upper/diag epilogue
  #pragma unroll
  for (int m = 0; m < 4; ++m)
    #pragma unroll
    for (int q = 0; q < 4; ++q) {
      int row = m0 + wr + m * 16 + lq * 4 + q;
      float s = 0.f;
      #pragma unroll
      for (int n = 0; n < 4; ++n) {
        int col = n0 + wc + n * 16 + l16;
        size_t idx = (size_t)row * Nn + col;
        float e = expf(bf2f(Gb[idx]) + acc[m][n][q]);
        Gexp[idx] = f2bf(e);
        s += e;
      }
      s += __shfl_xor(s, 1); s += __shfl_xor(s, 2);
      s += __shfl_xor(s, 4); s += __shfl_xor(s, 8);
      if (l16 == 0) atomicAdd(&rowsum[row], s);
    }
  if (bx == by) return;

  // mirrored (lower) epilogue via LDS transpose (Tg = 128*132 shorts = 33 KB, fits in SM)
  __syncthreads();
  unsigned short* Tg = SM;
  {
    int cc = tid >> 1, r0 = (tid & 1) * 64;
    const unsigned short* src = Gb + (size_t)(n0 + cc) * Nn + m0 + r0;
    unsigned short* dst = Tg + cc * 132 + r0;
    #pragma unroll
    for (int v = 0; v < 8; ++v)
      *reinterpret_cast<u16x8*>(dst + v * 8) = *reinterpret_cast<const u16x8*>(src + v * 8);
  }
  __syncthreads();
  #pragma unroll
  for (int n = 0; n < 4; ++n) {
    int ccl = wc + n * 16 + l16;
    float cs = 0.f;
    #pragma unroll
    for (int m = 0; m < 4; ++m) {
      int sa = ccl * 132 + wr + m * 16 + lq * 4;
      ushort4 lg = *reinterpret_cast<const ushort4*>(&Tg[sa]);
      ushort4 eo;
      float e0 = expf(bf2f(lg.x) + acc[m][n][0]); eo.x = f2bf(e0); cs += e0;
      float e1 = expf(bf2f(lg.y) + acc[m][n][1]); eo.y = f2bf(e1); cs += e1;
      float e2 = expf(bf2f(lg.z) + acc[m][n][2]); eo.z = f2bf(e2); cs += e2;
      float e3 = expf(bf2f(lg.w) + acc[m][n][3]); eo.w = f2bf(e3); cs += e3;
      *reinterpret_cast<ushort4*>(&Tg[sa]) = eo;
    }
    cs += __shfl_xor(cs, 16); cs += __shfl_xor(cs, 32);
    if (lq == 0) atomicAdd(&rowsum[n0 + ccl], cs);
  }
  __syncthreads();
  {
    int cc = tid >> 1, r0 = (tid & 1) * 64;
    const unsigned short* src = Tg + cc * 132 + r0;
    unsigned short* dst = Gexp + (size_t)(n0 + cc) * Nn + m0 + r0;
    #pragma unroll
    for (int v = 0; v < 8; ++v)
      *reinterpret_cast<u16x8*>(dst + v * 8) = *reinterpret_cast<const u16x8*>(src + v * 8);
  }
}

// ======== standalone 128x128 split-K atomic GEMM (M-gemm) ========
__global__ __launch_bounds__(256) void gemm_bts_bf16(
    const unsigned short* __restrict__ Ab, const unsigned short* __restrict__ Bb,
    float* __restrict__ Cp, int N, int lda, int ldb, int KS)
{
  __shared__ unsigned short SM[16384];
  bts_dev(Ab, Bb, Cp, N, lda, ldb, blockIdx.x * 128, blockIdx.y * 128,
          blockIdx.z * KS, KS >> 5, SM);
}

// ======== fused launch: z<8 z_g slices, z in {8,9} tewT slices ========
__global__ __launch_bounds__(256) void zgtew_k(
    const unsigned short* __restrict__ Gexp, const unsigned short* __restrict__ hgT,
    float* __restrict__ outzg,
    const unsigned short* __restrict__ hWT, const unsigned short* __restrict__ AhB,
    float* __restrict__ tewTf)
{
  __shared__ unsigned short SM[16384];
  int z = blockIdx.z;
  if (z < 8) {
    bts_dev(Gexp, hgT, outzg, Dd, Nn, Nn, blockIdx.x * 128, blockIdx.y * 128, z * 512, 16, SM);
  } else {
    int linear = (z - 8) * 64 + blockIdx.y * 32 + blockIdx.x;  // [0,128)
    int tile = linear & 15, ks = linear >> 4;
    int m0 = (tile >> 3) * 128, n0 = (tile & 7) * 128;
    bts_dev(hWT, AhB, tewTf, Ee, Nn, Nn, m0, n0, ks * 512, 16, SM);
  }
}

// ---------------- bf16 MFMA GEMM: C = alpha*(A*B^T), 128x128, BK=32 (+opt bf16 out) ----------------
__global__ __launch_bounds__(256) void gemm_bt_bf16(
    const unsigned short* __restrict__ Ab, const unsigned short* __restrict__ Bb,
    float* __restrict__ Cp, unsigned short* __restrict__ Cb,
    int M, int N, int K, int lda, int ldb, float alpha)
{
  __shared__ unsigned short As[2][128 * 32];
  __shared__ unsigned short Bs[2][128 * 32];
  const int tid = threadIdx.x;
  const int m0 = blockIdx.x * 128, n0 = blockIdx.y * 128;
  const int wave = tid >> 6, lane = tid & 63;
  const int wr = (wave >> 1) * 64, wc = (wave & 1) * 64;
  const int l16 = lane & 15, lq = lane >> 4;
  f32x4 acc[4][4] = {};
  const int NT = K >> 5;

  auto stage = [&](int buf, int kt) {
    const int k0 = kt * 32;
    #pragma unroll
    for (int i = 0; i < 2; ++i) {
      int t2 = tid + i * 256;
      int r = t2 >> 2, c = (t2 & 3) * 8;
      gload_lds16(Ab + (size_t)(m0 + r) * lda + k0 + c, &As[buf][t2 * 8]);
    }
    #pragma unroll
    for (int i = 0; i < 2; ++i) {
      int t2 = tid + i * 256;
      int r = t2 >> 2, c = (t2 & 3) * 8;
      gload_lds16(Bb + (size_t)(n0 + r) * ldb + k0 + c, &Bs[buf][t2 * 8]);
    }
  };

  stage(0, 0);
  __syncthreads();
  int buf = 0;
  for (int kt = 0; kt < NT; ++kt) {
    if (kt + 1 < NT) stage(buf ^ 1, kt + 1);
    bf16x8 af[4], bfr[4];
    #pragma unroll
    for (int m = 0; m < 4; ++m)
      af[m] = *reinterpret_cast<const bf16x8*>(&As[buf][(wr + m * 16 + l16) * 32 + lq * 8]);
    #pragma unroll
    for (int n = 0; n < 4; ++n)
      bfr[n] = *reinterpret_cast<const bf16x8*>(&Bs[buf][(wc + n * 16 + l16) * 32 + lq * 8]);
    #pragma unroll
    for (int m = 0; m < 4; ++m)
      #pragma unroll
      for (int n = 0; n < 4; ++n)
        acc[m][n] = __builtin_amdgcn_mfma_f32_16x16x32_bf16(af[m], bfr[n], acc[m][n], 0, 0, 0);
    __syncthreads();
    buf ^= 1;
  }
  #pragma unroll
  for (int m = 0; m < 4; ++m)
    #pragma unroll
    for (int n = 0; n < 4; ++n) {
      int col = n0 + wc + n * 16 + l16;
      #pragma unroll
      for (int q = 0; q < 4; ++q) {
        int row = m0 + wr + m * 16 + lq * 4 + q;
        size_t idx = (size_t)row * N + col;
        float v = acc[m][n][q] * alpha;
        Cp[idx] = v;
        if (Cb) Cb[idx] = f2bf(v);
      }
    }
}

// ---------------- bf16 MFMA GEMM, 64x64 tile, BK=64, split-K via atomicAdd ----------------
__global__ __launch_bounds__(256) void gemm64s_bt_bf16(
    const unsigned short* __restrict__ Ab, const unsigned short* __restrict__ Bb,
    float* __restrict__ Cp, int M, int N, int K, int KS)
{
  __shared__ unsigned short As[2][64 * 64];
  __shared__ unsigned short Bs[2][64 * 64];
  const int tid = threadIdx.x;
  const int m0 = blockIdx.x * 64, n0 = blockIdx.y * 64;
  const int kbase = blockIdx.z * KS;
  const int wave = tid >> 6, lane = tid & 63;
  const int wr = (wave >> 1) * 32, wc = (wave & 1) * 32;
  const int l16 = lane & 15, lq = lane >> 4;
  f32x4 acc[2][2] = {};
  const int NT = KS >> 6;

  auto stage = [&](int buf, int kt) {
    const int k0 = kbase + kt * 64;
    #pragma unroll
    for (int i = 0; i < 2; ++i) {
      int t2 = tid + i * 256;
      int r = t2 >> 3, c = (t2 & 7) * 8;
      gload_lds16(Ab + (size_t)(m0 + r) * K + k0 + c, &As[buf][t2 * 8]);
    }
    #pragma unroll
    for (int i = 0; i < 2; ++i) {
      int t2 = tid + i * 256;
      int r = t2 >> 3, c = (t2 & 7) * 8;
      gload_lds16(Bb + (size_t)(n0 + r) * K + k0 + c, &Bs[buf][t2 * 8]);
    }
  };

  stage(0, 0);
  __syncthreads();
  int buf = 0;
  for (int kt = 0; kt < NT; ++kt) {
    if (kt + 1 < NT) stage(buf ^ 1, kt + 1);
    bf16x8 af[2][2], bfr[2][2];
    #pragma unroll
    for (int m = 0; m < 2; ++m)
      #pragma unroll
      for (int ks = 0; ks < 2; ++ks)
        af[m][ks] = *reinterpret_cast<const bf16x8*>(
            &As[buf][(wr + m * 16 + l16) * 64 + ks * 32 + lq * 8]);
    #pragma unroll
    for (int n = 0; n < 2; ++n)
      #pragma unroll
      for (int ks = 0; ks < 2; ++ks)
        bfr[n][ks] = *reinterpret_cast<const bf16x8*>(
            &Bs[buf][(wc + n * 16 + l16) * 64 + ks * 32 + lq * 8]);
    #pragma unroll
    for (int m = 0; m < 2; ++m)
      #pragma unroll
      for (int n = 0; n < 2; ++n)
        #pragma unroll
        for (int ks = 0; ks < 2; ++ks)
          acc[m][n] = __builtin_amdgcn_mfma_f32_16x16x32_bf16(af[m][ks], bfr[n][ks], acc[m][n], 0, 0, 0);
    __syncthreads();
    buf ^= 1;
  }
  #pragma unroll
  for (int m = 0; m < 2; ++m)
    #pragma unroll
    for (int n = 0; n < 2; ++n) {
      int col = n0 + wc + n * 16 + l16;
      #pragma unroll
      for (int q = 0; q < 4; ++q) {
        int row = m0 + wr + m * 16 + lq * 4 + q;
        atomicAdd(&Cp[(size_t)row * N + col], acc[m][n][q]);
      }
    }
}

// ---------------- f32 -> bf16 convert ----------------
__global__ __launch_bounds__(256) void cvt_bf16_k(const float* __restrict__ in,
                                                  unsigned short* __restrict__ out, long n) {
  long i = ((long)blockIdx.x * 256 + threadIdx.x) * 8;
  if (i + 8 > n) return;
  float4 a = *reinterpret_cast<const float4*>(&in[i]);
  float4 b = *reinterpret_cast<const float4*>(&in[i + 4]);
  u16x8 o;
  o[0] = f2bf(a.x); o[1] = f2bf(a.y); o[2] = f2bf(a.z); o[3] = f2bf(a.w);
  o[4] = f2bf(b.x); o[5] = f2bf(b.y); o[6] = f2bf(b.z); o[7] = f2bf(b.w);
  *reinterpret_cast<u16x8*>(&out[i]) = o;
}

// ---------------- convert with per-column 1/aden scale (tewTf [Dd][Ee]) ----------------
__global__ __launch_bounds__(256) void cvt_cs_k(const float* __restrict__ in,
                                                unsigned short* __restrict__ out,
                                                const float* __restrict__ aden) {
  long i = ((long)blockIdx.x * 256 + threadIdx.x) * 8;
  int e0 = (int)(i & 1023);
  float4 a = *reinterpret_cast<const float4*>(&in[i]);
  float4 b = *reinterpret_cast<const float4*>(&in[i + 4]);
  float4 d0 = *reinterpret_cast<const float4*>(&aden[e0]);
  float4 d1 = *reinterpret_cast<const float4*>(&aden[e0 + 4]);
  u16x8 o;
  o[0] = f2bf(a.x / d0.x); o[1] = f2bf(a.y / d0.y); o[2] = f2bf(a.z / d0.z); o[3] = f2bf(a.w / d0.w);
  o[4] = f2bf(b.x / d1.x); o[5] = f2bf(b.y / d1.y); o[6] = f2bf(b.z / d1.z); o[7] = f2bf(b.w / d1.w);
  *reinterpret_cast<u16x8*>(&out[i]) = o;
}

// ---------------- transpose-convert f32 [R rows, S stride] -> bf16 [C][R], opt col scale ----------------
__global__ __launch_bounds__(256) void tcvt_k(const float* __restrict__ in,
                                              unsigned short* __restrict__ outT, int R, int S,
                                              const float* __restrict__ coldiv) {
  __shared__ unsigned short tile[64][65];
  int r0 = blockIdx.x * 64, c0 = blockIdx.y * 64;
  int t = threadIdx.x & 63, q = threadIdx.x >> 6;
  float sc = coldiv ? 1.f / fmaxf(coldiv[c0 + t], 1.f) : 1.f;
  for (int rr = q; rr < 64; rr += 4)
    tile[t][rr] = f2bf(in[(long)(r0 + rr) * S + c0 + t] * sc);
  __syncthreads();
  for (int cc = q; cc < 64; cc += 4)
    outT[(long)(c0 + cc) * R + r0 + t] = tile[cc][t];
}

// ---------------- 4x W transpose-convert in one launch ----------------
__global__ __launch_bounds__(256) void tcvtW_k(const float* __restrict__ W0,
                                               const float* __restrict__ W1,
                                               const float* __restrict__ W2,
                                               const float* __restrict__ W3,
                                               unsigned short* __restrict__ outT) {
  __shared__ unsigned short tile[64][65];
  int s = blockIdx.z;
  const float* in = s == 0 ? W0 : (s == 1 ? W1 : (s == 2 ? W2 : W3));
  unsigned short* o = outT + (size_t)s * 256 * 256;
  int r0 = blockIdx.x * 64, c0 = blockIdx.y * 64;
  int t = threadIdx.x & 63, q = threadIdx.x >> 6;
  for (int rr = q; rr < 64; rr += 4)
    tile[t][rr] = f2bf(in[(long)(r0 + rr) * Dd + c0 + t]);
  __syncthreads();
  for (int cc = q; cc < 64; cc += 4)
    o[(long)(c0 + cc) * Dd + r0 + t] = tile[cc][t];
}

// ---------------- 2x hcat4-slice transpose-convert ----------------
__global__ __launch_bounds__(256) void tcvtH_k(const float* __restrict__ hcat4,
                                               unsigned short* __restrict__ hWT,
                                               unsigned short* __restrict__ hgT) {
  __shared__ unsigned short tile[64][65];
  int s = blockIdx.z;
  const float* in = hcat4 + (s == 0 ? 768 : 512);
  unsigned short* o = s == 0 ? hWT : hgT;
  int r0 = blockIdx.x * 64, c0 = blockIdx.y * 64;
  int t = threadIdx.x & 63, q = threadIdx.x >> 6;
  for (int rr = q; rr < 64; rr += 4)
    tile[t][rr] = f2bf(in[(long)(r0 + rr) * 1024 + c0 + t]);
  __syncthreads();
  for (int cc = q; cc < 64; cc += 4)
    o[(long)(c0 + cc) * Nn + r0 + t] = tile[cc][t];
}

// ---------------- final: z_h rows /bden, z_g rows /rowsum, elu ----------------
__global__ __launch_bounds__(256) void elu_rows_k(float* __restrict__ p,
                                                  const float* __restrict__ bden,
                                                  const float* __restrict__ rowsum) {
  long i = ((long)blockIdx.x * 256 + threadIdx.x) * 4;
  float4 v = *reinterpret_cast<const float4*>(&p[i]);
  long half = (long)Nn * Dd;
  float sc = (i < half) ? 1.f / bden[i >> 8] : 1.f / rowsum[(i - half) >> 8];
  v.x *= sc; v.y *= sc; v.z *= sc; v.w *= sc;
  v.x = v.x > 0.f ? v.x : expm1f(v.x);
  v.y = v.y > 0.f ? v.y : expm1f(v.y);
  v.z = v.z > 0.f ? v.z : expm1f(v.z);
  v.w = v.w > 0.f ? v.w : expm1f(v.w);
  *reinterpret_cast<float4*>(&p[i]) = v;
}

// ---------------- generic strided f32 GEMM, 64x64 tile (Wp only) ----------------
__global__ __launch_bounds__(256) void gemm64_k(
    const float* __restrict__ Ap, const float* __restrict__ Bp, float* __restrict__ Cp,
    int M, int N, int K, int Asm, int Ask, int Bsk, int Bsn)
{
  __shared__ alignas(16) float As[16][68];
  __shared__ alignas(16) float Bs[16][68];
  const int tid = threadIdx.x;
  const int tx = tid & 15, ty = tid >> 4;
  const int m0 = blockIdx.x * 64, n0 = blockIdx.y * 64;
  float acc[4][4] = {};
  for (int k0 = 0; k0 < K; k0 += 16) {
    if (Ask == 1) {
      int mm = tid >> 2, kk = (tid & 3) << 2;
      float4 v = *reinterpret_cast<const float4*>(&Ap[(long)(m0 + mm) * Asm + k0 + kk]);
      As[kk + 0][mm] = v.x; As[kk + 1][mm] = v.y; As[kk + 2][mm] = v.z; As[kk + 3][mm] = v.w;
    } else {
      int kk = tid >> 4, mm = (tid & 15) << 2;
      *reinterpret_cast<float4*>(&As[kk][mm]) =
          *reinterpret_cast<const float4*>(&Ap[(long)(k0 + kk) * Ask + m0 + mm]);
    }
    if (Bsn == 1) {
      int kk = tid >> 4, nn = (tid & 15) << 2;
      *reinterpret_cast<float4*>(&Bs[kk][nn]) =
          *reinterpret_cast<const float4*>(&Bp[(long)(k0 + kk) * Bsk + n0 + nn]);
    } else {
      int nn = tid >> 2, kk = (tid & 3) << 2;
      float4 v = *reinterpret_cast<const float4*>(&Bp[(long)(n0 + nn) * Bsn + k0 + kk]);
      Bs[kk + 0][nn] = v.x; Bs[kk + 1][nn] = v.y; Bs[kk + 2][nn] = v.z; Bs[kk + 3][nn] = v.w;
    }
    __syncthreads();
    #pragma unroll
    for (int kk = 0; kk < 16; ++kk) {
      float4 av = *reinterpret_cast<const float4*>(&As[kk][ty << 2]);
      float4 bv = *reinterpret_cast<const float4*>(&Bs[kk][tx << 2]);
      float a[4] = {av.x, av.y, av.z, av.w};
      float b[4] = {bv.x, bv.y, bv.z, bv.w};
      #pragma unroll
      for (int r = 0; r < 4; ++r)
        #pragma unroll
        for (int c = 0; c < 4; ++c) acc[r][c] = fmaf(a[r], b[c], acc[r][c]);
    }
    __syncthreads();
  }
  #pragma unroll
  for (int r = 0; r < 4; ++r) {
    long base = (long)(m0 + (ty << 2) + r) * N + n0 + (tx << 2);
    float4 o = {acc[r][0], acc[r][1], acc[r][2], acc[r][3]};
    *reinterpret_cast<float4*>(&Cp[base]) = o;
  }
}

// ---------------- sc/s1/s2 row dots ----------------
__global__ __launch_bounds__(256) void rowdots_k(
    const float* __restrict__ hcat, const float* __restrict__ u, const float* __restrict__ a_g,
    float* __restrict__ esc, float* __restrict__ s1, float* __restrict__ s2)
{
  int i = blockIdx.x, t = threadIdx.x;
  float hh = hcat[(long)i * 1024 + t];
  float hg = hcat[(long)i * 1024 + 512 + t];
  float d0 = block_reduce_sum(hh * u[t]);
  float d1 = block_reduce_sum(hg * a_g[t]);
  float d2 = block_reduce_sum(hg * a_g[Dd + t]);
  if (t == 0) {
    esc[i] = expf(d0 * 0.0625f);
    s1[i] = d1;
    s2[i] = d2;
  }
}

// ---------------- column softmax stats for A ----------------
__global__ __launch_bounds__(256) void colstats_k(
    const float* __restrict__ H, const float* __restrict__ esc,
    float* __restrict__ colden, float* __restrict__ cnt)
{
  int e = blockIdx.x * 256 + threadIdx.x;
  int r0 = blockIdx.y * 128;
  float d = 0.f, c = 0.f;
  for (int r = r0; r < r0 + 128; ++r) {
    float h = H[(long)r * Ee + e];
    if (h > 0.f) { d += esc[r]; c += 1.f; }
  }
  atomicAdd(&colden[e], d);
  atomicAdd(&cnt[e], c);
}

// ---------------- A fill (tile): CAT A-half bf16 + AbT bf16 ----------------
__global__ __launch_bounds__(256) void fillA_k(
    const float* __restrict__ H, const float* __restrict__ esc,
    const float* __restrict__ colden,
    unsigned short* __restrict__ CAT, unsigned short* __restrict__ AbT)
{
  __shared__ unsigned short tile[64][68];
  int r0 = blockIdx.x * 64, e0 = blockIdx.y * 64;
  int te = threadIdx.x & 63, tq = threadIdx.x >> 6;
  float cd = colden[e0 + te];
  for (int rr = tq; rr < 64; rr += 4) {
    long idx = (long)(r0 + rr) * Ee + e0 + te;
    float h = H[idx];
    float val = h > 0.f ? esc[r0 + rr] / cd : 0.f;
    unsigned short vb = f2bf(val);
    CAT[(long)(r0 + rr) * 2048 + 1024 + e0 + te] = vb;
    tile[te][rr] = vb;
  }
  __syncthreads();
  for (int ee = tq; ee < 64; ee += 4)
    AbT[(long)(e0 + ee) * Nn + r0 + te] = tile[ee][te];
}

// ---------------- B row softmax: CAT B-half ----------------
__global__ __launch_bounds__(256) void brow_k(const float* __restrict__ Bbuf,
                                              const float* __restrict__ H,
                                              unsigned short* __restrict__ CAT)
{
  int i = blockIdx.x, t = threadIdx.x;
  long base = (long)i * Ee + t * 4;
  float4 raw = *reinterpret_cast<const float4*>(&Bbuf[base]);
  float4 h = *reinterpret_cast<const float4*>(&H[base]);
  float rr[4] = {raw.x, raw.y, raw.z, raw.w}, hh[4] = {h.x, h.y, h.z, h.w};
  float p[4]; float s = 0.f;
  #pragma unroll
  for (int k = 0; k < 4; ++k) { p[k] = hh[k] > 0.f ? expf(rr[k]) : 0.f; s += p[k]; }
  float den = block_reduce_sum(s);
  float inv = den > 0.f ? 1.f / den : 0.f;
  ushort4 ob = {f2bf(p[0] * inv), f2bf(p[1] * inv), f2bf(p[2] * inv), f2bf(p[3] * inv)};
  *reinterpret_cast<ushort4*>(&CAT[(long)i * 2048 + t * 4]) = ob;
}

// ---------------- G fill: bf16 probs ----------------
__global__ __launch_bounds__(256) void gfill_k(
    const float* __restrict__ adj, const float* __restrict__ s1,
    const float* __restrict__ s2, unsigned short* __restrict__ Gb)
{
  int i = blockIdx.x, t = threadIdx.x;
  float s1i = s1[i];
  float p[16]; float sum = 0.f;
  #pragma unroll
  for (int c = 0; c < 4; ++c) {
    int j = c * 1024 + t * 4;
    float4 a = *reinterpret_cast<const float4*>(&adj[(long)i * Nn + j]);
    float4 sv = *reinterpret_cast<const float4*>(&s2[j]);
    float aa[4] = {a.x, a.y, a.z, a.w}, ss[4] = {sv.x, sv.y, sv.z, sv.w};
    #pragma unroll
    for (int k = 0; k < 4; ++k) {
      float f = (aa[k] > 0.f ? 1.f : 0.f) + ((j + k) == i ? 1.f : 0.f);
      float l = s1i + ss[k];
      l = l > 0.f ? l : 0.2f * l;
      float val = l * f - 1e9f * fmaxf(1.f - f, 0.f);
      float pp = expf(val);
      p[c * 4 + k] = pp; sum += pp;
    }
  }
  float den = block_reduce_sum(sum);
  float inv = 1.f / den;
  #pragma unroll
  for (int c = 0; c < 4; ++c) {
    int j = c * 1024 + t * 4;
    ushort4 ob = {f2bf(p[c * 4] * inv), f2bf(p[c * 4 + 1] * inv),
                  f2bf(p[c * 4 + 2] * inv), f2bf(p[c * 4 + 3] * inv)};
    *reinterpret_cast<ushort4*>(&Gb[(long)i * Nn + j]) = ob;
  }
}

// ---------------- fused: Bb2 = exp(B+M)*mask (unnorm), bden rows, aden col atomics ----------------
__global__ __launch_bounds__(256) void expbm_k(
    const unsigned short* __restrict__ CAT, const float* __restrict__ Mm,
    const float* __restrict__ H, unsigned short* __restrict__ Bb2,
    float* __restrict__ bden, float* __restrict__ aden)
{
  int t = threadIdx.x;
  int i0 = blockIdx.x * 16;
  float pa[4] = {0.f, 0.f, 0.f, 0.f};
  for (int r = 0; r < 16; ++r) {
    int i = i0 + r;
    long base = (long)i * Ee + t * 4;
    ushort4 bu = *reinterpret_cast<const ushort4*>(&CAT[(long)i * 2048 + t * 4]);
    ushort4 au = *reinterpret_cast<const ushort4*>(&CAT[(long)i * 2048 + 1024 + t * 4]);
    float4 m = *reinterpret_cast<const float4*>(&Mm[base]);
    float4 h = *reinterpret_cast<const float4*>(&H[base]);
    float mm[4] = {m.x, m.y, m.z, m.w}, hh[4] = {h.x, h.y, h.z, h.w};
    unsigned short bs[4] = {bu.x, bu.y, bu.z, bu.w}, as[4] = {au.x, au.y, au.z, au.w};
    float eb[4]; float s = 0.f;
    #pragma unroll
    for (int k = 0; k < 4; ++k) {
      eb[k] = expf(bf2f(bs[k]) + mm[k]); s += eb[k];
      pa[k] += expf(bf2f(as[k]) + mm[k]);
    }
    float den = block_reduce_sum(s);
    ushort4 ob = {hh[0] > 0.f ? f2bf(eb[0]) : (unsigned short)0,
                  hh[1] > 0.f ? f2bf(eb[1]) : (unsigned short)0,
                  hh[2] > 0.f ? f2bf(eb[2]) : (unsigned short)0,
                  hh[3] > 0.f ? f2bf(eb[3]) : (unsigned short)0};
    *reinterpret_cast<ushort4*>(&Bb2[base]) = ob;
    if (t == 0) bden[i] = den;
  }
  #pragma unroll
  for (int k = 0; k < 4; ++k) atomicAdd(&aden[t * 4 + k], pa[k]);
}

// ---------------- A_hat fill (UNNORMALIZED, transpose, bf16 out) ----------------
__global__ __launch_bounds__(256) void ahat_k(
    const unsigned short* __restrict__ CAT, const float* __restrict__ Mm,
    const float* __restrict__ H, unsigned short* __restrict__ AhB)
{
  __shared__ float tile[64][65];
  int j0 = blockIdx.x * 64, e0 = blockIdx.y * 64;
  int te = threadIdx.x & 63;
  int tq = threadIdx.x >> 6;
  int e = e0 + te;
  for (int jj = tq; jj < 64; jj += 4) {
    long idx = (long)(j0 + jj) * Ee + e;
    float a = bf2f(CAT[(size_t)(j0 + jj) * 2048 + 1024 + e]);
    float val = (H[idx] > 0.f) ? expf(a + Mm[idx]) : 0.f;
    tile[te][jj] = val;
  }
  __syncthreads();
  for (int ee = tq; ee < 64; ee += 4)
    AhB[(long)(e0 + ee) * Nn + j0 + te] = f2bf(tile[ee][te]);
}

// ---------------- launcher ----------------
extern "C" void kernel_launch(void* const* d_in, const int* in_sizes, int n_in,
                              void* d_out, int out_size, void* d_ws, size_t ws_size,
                              hipStream_t stream) {
  const float* x    = (const float*)d_in[0];
  const float* H    = (const float*)d_in[1];
  const float* adj  = (const float*)d_in[2];
  const float* W_he = (const float*)d_in[3];
  const float* u    = (const float*)d_in[4];
  const float* W_e  = (const float*)d_in[5];
  const float* W_n  = (const float*)d_in[6];
  const float* W_g  = (const float*)d_in[7];
  const float* a_g  = (const float*)d_in[8];
  float* out = (float*)d_out;
  float* ws  = (float*)d_ws;
  (void)in_sizes; (void)n_in; (void)out_size; (void)ws_size;

  size_t off = 0;
  auto alloc = [&](size_t n) { float* p = ws + off; off += n; return p; };
  float* hcat4  = alloc((size_t)Nn * 1024);  // [h_he | hn | h_g | hW]
  float* Wp     = alloc((size_t)Dd * Dd);
  float* esc    = alloc(Nn);
  float* s1     = alloc(Nn);
  float* s2     = alloc(Nn);
  float* colden = alloc(Ee);   // colden,cnt,aden,rowsum,bden contiguous -> one memset
  float* cnt    = alloc(Ee);
  float* aden   = alloc(Ee);
  float* rowsum = alloc(Nn);
  float* bden   = alloc(Nn);
  float* heb    = alloc((size_t)Ee * Dd);    // heb,tewTf contiguous -> one memset
  float* tewTf  = alloc((size_t)Dd * Ee);
  float* Bbuf   = alloc((size_t)Nn * Ee);
  float* Mm     = alloc((size_t)Nn * Ee);
  unsigned short* Gb    = (unsigned short*)alloc((size_t)Nn * Nn / 2);
  unsigned short* Gexp  = (unsigned short*)alloc((size_t)Nn * Nn / 2);
  unsigned short* CAT   = (unsigned short*)alloc((size_t)Nn * 2048 / 2);
  unsigned short* Hbt   = (unsigned short*)alloc((size_t)Ee * Nn / 2);
  unsigned short* AbT   = (unsigned short*)alloc((size_t)Ee * Nn / 2);
  unsigned short* AhB   = (unsigned short*)alloc((size_t)Ee * Nn / 2);
  unsigned short* hWT   = (unsigned short*)alloc((size_t)Dd * Nn / 2);
  unsigned short* hgT   = (unsigned short*)alloc((size_t)Dd * Nn / 2);
  unsigned short* tewT  = (unsigned short*)alloc((size_t)Dd * Ee / 2);
  unsigned short* Bb2   = (unsigned short*)alloc((size_t)Nn * Ee / 2);
  unsigned short* xb    = (unsigned short*)alloc((size_t)Nn * Dd / 2);
  unsigned short* WcTb4 = (unsigned short*)alloc((size_t)1024 * Dd / 2);
  unsigned short* hcatB = (unsigned short*)alloc((size_t)Nn * 1024 / 2);
  unsigned short* hebB  = (unsigned short*)alloc((size_t)Ee * Dd / 2);

  hipMemsetAsync(colden, 0, (3 * Ee + 2 * Nn) * sizeof(float), stream);
  hipMemsetAsync(heb, 0, 2 * (size_t)Ee * Dd * sizeof(float), stream);
  hipMemsetAsync(Mm, 0, (size_t)Nn * Ee * sizeof(float), stream);
  hipMemsetAsync(out, 0, 2 * (size_t)Nn * Dd * sizeof(float), stream);

  auto gbt = [&](const unsigned short* A, const unsigned short* B, float* C, unsigned short* Cb,
                 int M, int N, int K, int lda, int ldb, float alpha) {
    gemm_bt_bf16<<<dim3(M / 128, N / 128), 256, 0, stream>>>(A, B, C, Cb, M, N, K, lda, ldb, alpha);
  };
  auto gs64 = [&](const unsigned short* A, const unsigned short* B, float* C,
                  int M, int N, int K, int KS) {
    gemm64s_bt_bf16<<<dim3(M / 64, N / 64, K / KS), 256, 0, stream>>>(A, B, C, M, N, K, KS);
  };
  auto tcvt = [&](const float* in, unsigned short* o, int R, int S, int cols, const float* cd) {
    tcvt_k<<<dim3(R / 64, cols / 64), 256, 0, stream>>>(in, o, R, S, cd);
  };

  // Wp = W_he @ W_e (tiny f32)
  gemm64_k<<<dim3(4, 4), 256, 0, stream>>>(W_he, W_e, Wp, Dd, Dd, Dd, Dd, 1, Dd, 1);
  // bf16 operands
  cvt_bf16_k<<<(Nn * Dd) / 2048, 256, 0, stream>>>(x, xb, (long)Nn * Dd);
  tcvtW_k<<<dim3(4, 4, 4), 256, 0, stream>>>(W_he, W_n, W_g, Wp, WcTb4);
  // fused projections
  gbt(xb, WcTb4, hcat4, hcatB, Nn, 1024, Dd, Dd, Dd, 1.f);
  rowdots_k<<<Nn, 256, 0, stream>>>(hcat4, u, a_g, esc, s1, s2);
  tcvtH_k<<<dim3(Nn / 64, Dd / 64, 2), 256, 0, stream>>>(hcat4, hWT, hgT);
  // A column softmax
  colstats_k<<<dim3(Ee / 256, 32), 256, 0, stream>>>(H, esc, colden, cnt);
  fillA_k<<<dim3(Nn / 64, Ee / 64), 256, 0, stream>>>(H, esc, colden, CAT, AbT);
  // heb = A^T @ hW  (split-K, 512 blocks)
  gs64(AbT, hWT, heb, Ee, Dd, Nn, 512);
  cvt_bf16_k<<<(Ee * Dd) / 2048, 256, 0, stream>>>(heb, hebB, (long)Ee * Dd);
  // Bsc = (hn @ heb^T)/16, row softmax -> CAT B-half
  gbt(hcatB + 256, hebB, Bbuf, nullptr, Nn, Ee, Dd, 1024, Dd, 0.0625f);
  brow_k<<<Nn, 256, 0, stream>>>(Bbuf, H, CAT);
  // G softmax -> bf16 probs
  gfill_k<<<Nn, 256, 0, stream>>>(adj, s1, s2, Gb);
  // M = G @ (H/he_sz): pre-scaled Hbt, split-K atomic (512 blocks)
  tcvt(H, Hbt, Nn, Ee, Ee, cnt);
  gemm_bts_bf16<<<dim3(32, 8, 2), 256, 0, stream>>>(Gb, Hbt, Mm, Ee, Nn, Nn, 2048);
  // symmetric gram BK=64: Gexp = exp(Gb + BB^T + AA^T), rowsum
  gram_k<<<dim3(32, 32), 256, 0, stream>>>(CAT, Gb, Gexp, rowsum);
  // fused exp(B+M) + bden + aden
  expbm_k<<<256, 256, 0, stream>>>(CAT, Mm, H, Bb2, bden, aden);
  // A_hat unnormalized transpose
  ahat_k<<<dim3(Nn / 64, Ee / 64), 256, 0, stream>>>(CAT, Mm, H, AhB);
  // FUSED: z_g = Gexp @ hgT (unnorm)  ||  tewTf = hWT @ AhB^T (unnorm)
  zgtew_k<<<dim3(32, 2, 10), 256, 0, stream>>>(Gexp, hgT, out + (size_t)Nn * Dd, hWT, AhB, tewTf);
  // tewT = bf16(tewTf / aden[col])
  cvt_cs_k<<<(Dd * Ee) / 2048, 256, 0, stream>>>(tewTf, tewT, aden);
  // z_h (unnorm) = Bb2 @ tewT
  gs64(Bb2, tewT, out, Nn, Dd, Ee, 512);
  // normalize rows + elu
  elu_rows_k<<<(2 * Nn * Dd) / 1024, 256, 0, stream>>>(out, bden, rowsum);
}

// Round 13
// 579.492 us; speedup vs baseline: 1.0553x; 1.0553x over previous
//
#include <hip/hip_runtime.h>
#include <math.h>
#include <stdint.h>

#define Nn 4096
#define Ee 1024
#define Dd 256

typedef __attribute__((ext_vector_type(8))) __bf16 bf16x8;
typedef __attribute__((ext_vector_type(4))) float f32x4;
typedef __attribute__((ext_vector_type(8))) unsigned short u16x8;

__device__ __forceinline__ unsigned short f2bf(float f) {
  unsigned int u = __float_as_uint(f);
  unsigned int r = (u + 0x7fffu + ((u >> 16) & 1u)) >> 16;
  return (unsigned short)r;
}
__device__ __forceinline__ float bf2f(unsigned short u) {
  return __uint_as_float(((unsigned int)u) << 16);
}

__device__ __forceinline__ void gload_lds16(const void* g, void* l) {
  __builtin_amdgcn_global_load_lds(
      (__attribute__((address_space(1))) void*)const_cast<void*>(g),
      (__attribute__((address_space(3))) void*)l, 16, 0, 0);
}

__device__ __forceinline__ float block_reduce_sum(float v) {
  __shared__ float sh[4];
  #pragma unroll
  for (int o = 32; o > 0; o >>= 1) v += __shfl_down(v, o);
  int lane = threadIdx.x & 63, w = threadIdx.x >> 6;
  if (lane == 0) sh[w] = v;
  __syncthreads();
  float s = sh[0] + sh[1] + sh[2] + sh[3];
  __syncthreads();
  return s;
}

// ---------------- bf16 MFMA GEMM: C = alpha*(A*B^T), 128x128, BK=32 (+opt bf16 out) ----------------
__global__ __launch_bounds__(256) void gemm_bt_bf16(
    const unsigned short* __restrict__ Ab, const unsigned short* __restrict__ Bb,
    float* __restrict__ Cp, unsigned short* __restrict__ Cb,
    int M, int N, int K, int lda, int ldb, float alpha)
{
  __shared__ unsigned short As[2][128 * 32];
  __shared__ unsigned short Bs[2][128 * 32];
  const int tid = threadIdx.x;
  const int m0 = blockIdx.x * 128, n0 = blockIdx.y * 128;
  const int wave = tid >> 6, lane = tid & 63;
  const int wr = (wave >> 1) * 64, wc = (wave & 1) * 64;
  const int l16 = lane & 15, lq = lane >> 4;
  f32x4 acc[4][4] = {};
  const int NT = K >> 5;

  auto stage = [&](int buf, int kt) {
    const int k0 = kt * 32;
    #pragma unroll
    for (int i = 0; i < 2; ++i) {
      int t2 = tid + i * 256;
      int r = t2 >> 2, c = (t2 & 3) * 8;
      gload_lds16(Ab + (size_t)(m0 + r) * lda + k0 + c, &As[buf][t2 * 8]);
    }
    #pragma unroll
    for (int i = 0; i < 2; ++i) {
      int t2 = tid + i * 256;
      int r = t2 >> 2, c = (t2 & 3) * 8;
      gload_lds16(Bb + (size_t)(n0 + r) * ldb + k0 + c, &Bs[buf][t2 * 8]);
    }
  };

  stage(0, 0);
  __syncthreads();
  int buf = 0;
  for (int kt = 0; kt < NT; ++kt) {
    if (kt + 1 < NT) stage(buf ^ 1, kt + 1);
    bf16x8 af[4], bfr[4];
    #pragma unroll
    for (int m = 0; m < 4; ++m)
      af[m] = *reinterpret_cast<const bf16x8*>(&As[buf][(wr + m * 16 + l16) * 32 + lq * 8]);
    #pragma unroll
    for (int n = 0; n < 4; ++n)
      bfr[n] = *reinterpret_cast<const bf16x8*>(&Bs[buf][(wc + n * 16 + l16) * 32 + lq * 8]);
    #pragma unroll
    for (int m = 0; m < 4; ++m)
      #pragma unroll
      for (int n = 0; n < 4; ++n)
        acc[m][n] = __builtin_amdgcn_mfma_f32_16x16x32_bf16(af[m], bfr[n], acc[m][n], 0, 0, 0);
    __syncthreads();
    buf ^= 1;
  }
  #pragma unroll
  for (int m = 0; m < 4; ++m)
    #pragma unroll
    for (int n = 0; n < 4; ++n) {
      int col = n0 + wc + n * 16 + l16;
      #pragma unroll
      for (int q = 0; q < 4; ++q) {
        int row = m0 + wr + m * 16 + lq * 4 + q;
        size_t idx = (size_t)row * N + col;
        float v = acc[m][n][q] * alpha;
        Cp[idx] = v;
        if (Cb) Cb[idx] = f2bf(v);
      }
    }
}

// ---------------- bf16 MFMA GEMM, 128x128 tile, BK=32, split-K atomicAdd ----------------
__global__ __launch_bounds__(256) void gemm_bts_bf16(
    const unsigned short* __restrict__ Ab, const unsigned short* __restrict__ Bb,
    float* __restrict__ Cp, int M, int N, int K, int lda, int ldb, int KS)
{
  __shared__ unsigned short As[2][128 * 32];
  __shared__ unsigned short Bs[2][128 * 32];
  const int tid = threadIdx.x;
  const int m0 = blockIdx.x * 128, n0 = blockIdx.y * 128;
  const int kbase = blockIdx.z * KS;
  const int wave = tid >> 6, lane = tid & 63;
  const int wr = (wave >> 1) * 64, wc = (wave & 1) * 64;
  const int l16 = lane & 15, lq = lane >> 4;
  f32x4 acc[4][4] = {};
  const int NT = KS >> 5;

  auto stage = [&](int buf, int kt) {
    const int k0 = kbase + kt * 32;
    #pragma unroll
    for (int i = 0; i < 2; ++i) {
      int t2 = tid + i * 256;
      int r = t2 >> 2, c = (t2 & 3) * 8;
      gload_lds16(Ab + (size_t)(m0 + r) * lda + k0 + c, &As[buf][t2 * 8]);
    }
    #pragma unroll
    for (int i = 0; i < 2; ++i) {
      int t2 = tid + i * 256;
      int r = t2 >> 2, c = (t2 & 3) * 8;
      gload_lds16(Bb + (size_t)(n0 + r) * ldb + k0 + c, &Bs[buf][t2 * 8]);
    }
  };

  stage(0, 0);
  __syncthreads();
  int buf = 0;
  for (int kt = 0; kt < NT; ++kt) {
    if (kt + 1 < NT) stage(buf ^ 1, kt + 1);
    bf16x8 af[4], bfr[4];
    #pragma unroll
    for (int m = 0; m < 4; ++m)
      af[m] = *reinterpret_cast<const bf16x8*>(&As[buf][(wr + m * 16 + l16) * 32 + lq * 8]);
    #pragma unroll
    for (int n = 0; n < 4; ++n)
      bfr[n] = *reinterpret_cast<const bf16x8*>(&Bs[buf][(wc + n * 16 + l16) * 32 + lq * 8]);
    #pragma unroll
    for (int m = 0; m < 4; ++m)
      #pragma unroll
      for (int n = 0; n < 4; ++n)
        acc[m][n] = __builtin_amdgcn_mfma_f32_16x16x32_bf16(af[m], bfr[n], acc[m][n], 0, 0, 0);
    __syncthreads();
    buf ^= 1;
  }
  #pragma unroll
  for (int m = 0; m < 4; ++m)
    #pragma unroll
    for (int n = 0; n < 4; ++n) {
      int col = n0 + wc + n * 16 + l16;
      #pragma unroll
      for (int q = 0; q < 4; ++q) {
        int row = m0 + wr + m * 16 + lq * 4 + q;
        atomicAdd(&Cp[(size_t)row * N + col], acc[m][n][q]);
      }
    }
}

// ======== symmetric fused Gram, BK=64 dbuf + XOR-swizzled LDS (conflict-free reads) ========
// Layout: logical (row r, 16B-chunk j) stored at physical chunk j^(r&7).
// global_load_lds keeps LDS linear; the swizzle is applied to the GLOBAL source and
// to the ds_read address by the same involution (rule #21).
__global__ __launch_bounds__(256) void gemm_gram_k(
    const unsigned short* __restrict__ CAT,   // [Nn][2048] bf16
    unsigned short* __restrict__ Gb,          // in: bf16 logits; out: exp(logit)
    float* __restrict__ rowsum)               // pre-zeroed [Nn]
{
  const int bx = blockIdx.x, by = blockIdx.y;
  if (bx > by) return;
  const int K = 2048;
  __shared__ unsigned short SM[32768];        // 64 KB: [2][8192] A + [2][8192] B
  unsigned short* Asb = SM;
  unsigned short* Bsb = SM + 16384;
  const int tid = threadIdx.x;
  const int m0 = bx * 128, n0 = by * 128;
  const int wave = tid >> 6, lane = tid & 63;
  const int wr = (wave >> 1) * 64, wc = (wave & 1) * 64;
  const int l16 = lane & 15, lq = lane >> 4;
  f32x4 acc[4][4] = {};
  const int NT = K >> 6;                      // 32

  auto stage = [&](int buf, int kt) {
    const int k0 = kt * 64;
    #pragma unroll
    for (int i = 0; i < 4; ++i) {
      int t2 = tid + i * 256;                 // 0..1023
      int r = t2 >> 3;                        // row 0..127
      int j = (t2 & 7) ^ (r & 7);             // pre-swizzled logical chunk
      gload_lds16(CAT + (size_t)(m0 + r) * K + k0 + j * 8, Asb + buf * 8192 + t2 * 8);
    }
    #pragma unroll
    for (int i = 0; i < 4; ++i) {
      int t2 = tid + i * 256;
      int r = t2 >> 3;
      int j = (t2 & 7) ^ (r & 7);
      gload_lds16(CAT + (size_t)(n0 + r) * K + k0 + j * 8, Bsb + buf * 8192 + t2 * 8);
    }
  };

  stage(0, 0);
  __syncthreads();
  int buf = 0;
  for (int kt = 0; kt < NT; ++kt) {
    if (kt + 1 < NT) stage(buf ^ 1, kt + 1);
    #pragma unroll
    for (int ks = 0; ks < 2; ++ks) {
      bf16x8 af[4], bfr[4];
      #pragma unroll
      for (int m = 0; m < 4; ++m) {
        int R = wr + m * 16 + l16;
        int ch = (ks * 4 + lq) ^ (R & 7);
        af[m] = *reinterpret_cast<const bf16x8*>(Asb + buf * 8192 + R * 64 + ch * 8);
      }
      #pragma unroll
      for (int n = 0; n < 4; ++n) {
        int R = wc + n * 16 + l16;
        int ch = (ks * 4 + lq) ^ (R & 7);
        bfr[n] = *reinterpret_cast<const bf16x8*>(Bsb + buf * 8192 + R * 64 + ch * 8);
      }
      #pragma unroll
      for (int m = 0; m < 4; ++m)
        #pragma unroll
        for (int n = 0; n < 4; ++n)
          acc[m][n] = __builtin_amdgcn_mfma_f32_16x16x32_bf16(af[m], bfr[n], acc[m][n], 0, 0, 0);
    }
    __syncthreads();
    buf ^= 1;
  }
  // normal epilogue (upper/diag region)
  #pragma unroll
  for (int m = 0; m < 4; ++m)
    #pragma unroll
    for (int q = 0; q < 4; ++q) {
      int row = m0 + wr + m * 16 + lq * 4 + q;
      float s = 0.f;
      #pragma unroll
      for (int n = 0; n < 4; ++n) {
        int col = n0 + wc + n * 16 + l16;
        size_t idx = (size_t)row * Nn + col;
        float e = expf(bf2f(Gb[idx]) + acc[m][n][q]);
        Gb[idx] = f2bf(e);
        s += e;
      }
      s += __shfl_xor(s, 1); s += __shfl_xor(s, 2);
      s += __shfl_xor(s, 4); s += __shfl_xor(s, 8);
      if (l16 == 0) atomicAdd(&rowsum[row], s);
    }
  if (bx == by) return;

  // transposed epilogue (lower region): mirror tile via LDS (Tg = 128*132 shorts, fits)
  __syncthreads();
  unsigned short* Tg = SM;
  {
    int cc = tid >> 1, r0 = (tid & 1) * 64;
    const unsigned short* src = Gb + (size_t)(n0 + cc) * Nn + m0 + r0;
    unsigned short* dst = Tg + cc * 132 + r0;
    #pragma unroll
    for (int v = 0; v < 8; ++v)
      *reinterpret_cast<u16x8*>(dst + v * 8) = *reinterpret_cast<const u16x8*>(src + v * 8);
  }
  __syncthreads();
  #pragma unroll
  for (int n = 0; n < 4; ++n) {
    int ccl = wc + n * 16 + l16;
    float cs = 0.f;
    #pragma unroll
    for (int m = 0; m < 4; ++m) {
      int sa = ccl * 132 + wr + m * 16 + lq * 4;
      ushort4 lg = *reinterpret_cast<const ushort4*>(&Tg[sa]);
      ushort4 eo;
      float e0 = expf(bf2f(lg.x) + acc[m][n][0]); eo.x = f2bf(e0); cs += e0;
      float e1 = expf(bf2f(lg.y) + acc[m][n][1]); eo.y = f2bf(e1); cs += e1;
      float e2 = expf(bf2f(lg.z) + acc[m][n][2]); eo.z = f2bf(e2); cs += e2;
      float e3 = expf(bf2f(lg.w) + acc[m][n][3]); eo.w = f2bf(e3); cs += e3;
      *reinterpret_cast<ushort4*>(&Tg[sa]) = eo;
    }
    cs += __shfl_xor(cs, 16); cs += __shfl_xor(cs, 32);
    if (lq == 0) atomicAdd(&rowsum[n0 + ccl], cs);
  }
  __syncthreads();
  {
    int cc = tid >> 1, r0 = (tid & 1) * 64;
    const unsigned short* src = Tg + cc * 132 + r0;
    unsigned short* dst = Gb + (size_t)(n0 + cc) * Nn + m0 + r0;
    #pragma unroll
    for (int v = 0; v < 8; ++v)
      *reinterpret_cast<u16x8*>(dst + v * 8) = *reinterpret_cast<const u16x8*>(src + v * 8);
  }
}

// ---------------- bf16 MFMA GEMM, 64x64 tile, BK=64, split-K via atomicAdd ----------------
__global__ __launch_bounds__(256) void gemm64s_bt_bf16(
    const unsigned short* __restrict__ Ab, const unsigned short* __restrict__ Bb,
    float* __restrict__ Cp, int M, int N, int K, int KS)
{
  __shared__ unsigned short As[2][64 * 64];
  __shared__ unsigned short Bs[2][64 * 64];
  const int tid = threadIdx.x;
  const int m0 = blockIdx.x * 64, n0 = blockIdx.y * 64;
  const int kbase = blockIdx.z * KS;
  const int wave = tid >> 6, lane = tid & 63;
  const int wr = (wave >> 1) * 32, wc = (wave & 1) * 32;
  const int l16 = lane & 15, lq = lane >> 4;
  f32x4 acc[2][2] = {};
  const int NT = KS >> 6;

  auto stage = [&](int buf, int kt) {
    const int k0 = kbase + kt * 64;
    #pragma unroll
    for (int i = 0; i < 2; ++i) {
      int t2 = tid + i * 256;
      int r = t2 >> 3, c = (t2 & 7) * 8;
      gload_lds16(Ab + (size_t)(m0 + r) * K + k0 + c, &As[buf][t2 * 8]);
    }
    #pragma unroll
    for (int i = 0; i < 2; ++i) {
      int t2 = tid + i * 256;
      int r = t2 >> 3, c = (t2 & 7) * 8;
      gload_lds16(Bb + (size_t)(n0 + r) * K + k0 + c, &Bs[buf][t2 * 8]);
    }
  };

  stage(0, 0);
  __syncthreads();
  int buf = 0;
  for (int kt = 0; kt < NT; ++kt) {
    if (kt + 1 < NT) stage(buf ^ 1, kt + 1);
    bf16x8 af[2][2], bfr[2][2];
    #pragma unroll
    for (int m = 0; m < 2; ++m)
      #pragma unroll
      for (int ks = 0; ks < 2; ++ks)
        af[m][ks] = *reinterpret_cast<const bf16x8*>(
            &As[buf][(wr + m * 16 + l16) * 64 + ks * 32 + lq * 8]);
    #pragma unroll
    for (int n = 0; n < 2; ++n)
      #pragma unroll
      for (int ks = 0; ks < 2; ++ks)
        bfr[n][ks] = *reinterpret_cast<const bf16x8*>(
            &Bs[buf][(wc + n * 16 + l16) * 64 + ks * 32 + lq * 8]);
    #pragma unroll
    for (int m = 0; m < 2; ++m)
      #pragma unroll
      for (int n = 0; n < 2; ++n)
        #pragma unroll
        for (int ks = 0; ks < 2; ++ks)
          acc[m][n] = __builtin_amdgcn_mfma_f32_16x16x32_bf16(af[m][ks], bfr[n][ks], acc[m][n], 0, 0, 0);
    __syncthreads();
    buf ^= 1;
  }
  #pragma unroll
  for (int m = 0; m < 2; ++m)
    #pragma unroll
    for (int n = 0; n < 2; ++n) {
      int col = n0 + wc + n * 16 + l16;
      #pragma unroll
      for (int q = 0; q < 4; ++q) {
        int row = m0 + wr + m * 16 + lq * 4 + q;
        atomicAdd(&Cp[(size_t)row * N + col], acc[m][n][q]);
      }
    }
}

// ---------------- f32 -> bf16 convert ----------------
__global__ __launch_bounds__(256) void cvt_bf16_k(const float* __restrict__ in,
                                                  unsigned short* __restrict__ out, long n) {
  long i = ((long)blockIdx.x * 256 + threadIdx.x) * 8;
  if (i + 8 > n) return;
  float4 a = *reinterpret_cast<const float4*>(&in[i]);
  float4 b = *reinterpret_cast<const float4*>(&in[i + 4]);
  u16x8 o;
  o[0] = f2bf(a.x); o[1] = f2bf(a.y); o[2] = f2bf(a.z); o[3] = f2bf(a.w);
  o[4] = f2bf(b.x); o[5] = f2bf(b.y); o[6] = f2bf(b.z); o[7] = f2bf(b.w);
  *reinterpret_cast<u16x8*>(&out[i]) = o;
}

// ---------------- transpose-convert f32 [R rows, S stride] -> bf16 [C][R], opt col scale ----------------
__global__ __launch_bounds__(256) void tcvt_k(const float* __restrict__ in,
                                              unsigned short* __restrict__ outT, int R, int S,
                                              const float* __restrict__ coldiv) {
  __shared__ unsigned short tile[64][65];
  int r0 = blockIdx.x * 64, c0 = blockIdx.y * 64;
  int t = threadIdx.x & 63, q = threadIdx.x >> 6;
  float sc = coldiv ? 1.f / fmaxf(coldiv[c0 + t], 1.f) : 1.f;
  for (int rr = q; rr < 64; rr += 4)
    tile[t][rr] = f2bf(in[(long)(r0 + rr) * S + c0 + t] * sc);
  __syncthreads();
  for (int cc = q; cc < 64; cc += 4)
    outT[(long)(c0 + cc) * R + r0 + t] = tile[cc][t];
}

// ---------------- 4x W transpose-convert (256x256 each) in one launch ----------------
__global__ __launch_bounds__(256) void tcvtW_k(const float* __restrict__ W0,
                                               const float* __restrict__ W1,
                                               const float* __restrict__ W2,
                                               const float* __restrict__ W3,
                                               unsigned short* __restrict__ outT) {
  __shared__ unsigned short tile[64][65];
  int s = blockIdx.z;
  const float* in = s == 0 ? W0 : (s == 1 ? W1 : (s == 2 ? W2 : W3));
  unsigned short* o = outT + (size_t)s * 256 * 256;
  int r0 = blockIdx.x * 64, c0 = blockIdx.y * 64;
  int t = threadIdx.x & 63, q = threadIdx.x >> 6;
  for (int rr = q; rr < 64; rr += 4)
    tile[t][rr] = f2bf(in[(long)(r0 + rr) * Dd + c0 + t]);
  __syncthreads();
  for (int cc = q; cc < 64; cc += 4)
    o[(long)(c0 + cc) * Dd + r0 + t] = tile[cc][t];
}

// ---------------- 2x hcat4-slice transpose-convert (hW->hWT, h_g->hgT) ----------------
__global__ __launch_bounds__(256) void tcvtH_k(const float* __restrict__ hcat4,
                                               unsigned short* __restrict__ hWT,
                                               unsigned short* __restrict__ hgT) {
  __shared__ unsigned short tile[64][65];
  int s = blockIdx.z;
  const float* in = hcat4 + (s == 0 ? 768 : 512);
  unsigned short* o = s == 0 ? hWT : hgT;
  int r0 = blockIdx.x * 64, c0 = blockIdx.y * 64;
  int t = threadIdx.x & 63, q = threadIdx.x >> 6;
  for (int rr = q; rr < 64; rr += 4)
    tile[t][rr] = f2bf(in[(long)(r0 + rr) * 1024 + c0 + t]);
  __syncthreads();
  for (int cc = q; cc < 64; cc += 4)
    o[(long)(c0 + cc) * Nn + r0 + t] = tile[cc][t];
}

// ---------------- final: scale z_g rows by 1/rowsum, elu both halves ----------------
__global__ __launch_bounds__(256) void elu_rows_k(float* __restrict__ p,
                                                  const float* __restrict__ rowsum) {
  long i = ((long)blockIdx.x * 256 + threadIdx.x) * 4;
  float4 v = *reinterpret_cast<const float4*>(&p[i]);
  float sc = 1.f;
  long half = (long)Nn * Dd;
  if (i >= half) sc = 1.f / rowsum[(i - half) >> 8];
  v.x *= sc; v.y *= sc; v.z *= sc; v.w *= sc;
  v.x = v.x > 0.f ? v.x : expm1f(v.x);
  v.y = v.y > 0.f ? v.y : expm1f(v.y);
  v.z = v.z > 0.f ? v.z : expm1f(v.z);
  v.w = v.w > 0.f ? v.w : expm1f(v.w);
  *reinterpret_cast<float4*>(&p[i]) = v;
}

// ---------------- generic strided f32 GEMM, 64x64 tile (Wp only) ----------------
__global__ __launch_bounds__(256) void gemm64_k(
    const float* __restrict__ Ap, const float* __restrict__ Bp, float* __restrict__ Cp,
    int M, int N, int K, int Asm, int Ask, int Bsk, int Bsn)
{
  __shared__ alignas(16) float As[16][68];
  __shared__ alignas(16) float Bs[16][68];
  const int tid = threadIdx.x;
  const int tx = tid & 15, ty = tid >> 4;
  const int m0 = blockIdx.x * 64, n0 = blockIdx.y * 64;
  float acc[4][4] = {};
  for (int k0 = 0; k0 < K; k0 += 16) {
    if (Ask == 1) {
      int mm = tid >> 2, kk = (tid & 3) << 2;
      float4 v = *reinterpret_cast<const float4*>(&Ap[(long)(m0 + mm) * Asm + k0 + kk]);
      As[kk + 0][mm] = v.x; As[kk + 1][mm] = v.y; As[kk + 2][mm] = v.z; As[kk + 3][mm] = v.w;
    } else {
      int kk = tid >> 4, mm = (tid & 15) << 2;
      *reinterpret_cast<float4*>(&As[kk][mm]) =
          *reinterpret_cast<const float4*>(&Ap[(long)(k0 + kk) * Ask + m0 + mm]);
    }
    if (Bsn == 1) {
      int kk = tid >> 4, nn = (tid & 15) << 2;
      *reinterpret_cast<float4*>(&Bs[kk][nn]) =
          *reinterpret_cast<const float4*>(&Bp[(long)(k0 + kk) * Bsk + n0 + nn]);
    } else {
      int nn = tid >> 2, kk = (tid & 3) << 2;
      float4 v = *reinterpret_cast<const float4*>(&Bp[(long)(n0 + nn) * Bsn + k0 + kk]);
      Bs[kk + 0][nn] = v.x; Bs[kk + 1][nn] = v.y; Bs[kk + 2][nn] = v.z; Bs[kk + 3][nn] = v.w;
    }
    __syncthreads();
    #pragma unroll
    for (int kk = 0; kk < 16; ++kk) {
      float4 av = *reinterpret_cast<const float4*>(&As[kk][ty << 2]);
      float4 bv = *reinterpret_cast<const float4*>(&Bs[kk][tx << 2]);
      float a[4] = {av.x, av.y, av.z, av.w};
      float b[4] = {bv.x, bv.y, bv.z, bv.w};
      #pragma unroll
      for (int r = 0; r < 4; ++r)
        #pragma unroll
        for (int c = 0; c < 4; ++c) acc[r][c] = fmaf(a[r], b[c], acc[r][c]);
    }
    __syncthreads();
  }
  #pragma unroll
  for (int r = 0; r < 4; ++r) {
    long base = (long)(m0 + (ty << 2) + r) * N + n0 + (tx << 2);
    float4 o = {acc[r][0], acc[r][1], acc[r][2], acc[r][3]};
    *reinterpret_cast<float4*>(&Cp[base]) = o;
  }
}

// ---------------- sc/s1/s2 row dots (hcat4 stride 1024) ----------------
__global__ __launch_bounds__(256) void rowdots_k(
    const float* __restrict__ hcat, const float* __restrict__ u, const float* __restrict__ a_g,
    float* __restrict__ esc, float* __restrict__ s1, float* __restrict__ s2)
{
  int i = blockIdx.x, t = threadIdx.x;
  float hh = hcat[(long)i * 1024 + t];
  float hg = hcat[(long)i * 1024 + 512 + t];
  float d0 = block_reduce_sum(hh * u[t]);
  float d1 = block_reduce_sum(hg * a_g[t]);
  float d2 = block_reduce_sum(hg * a_g[Dd + t]);
  if (t == 0) {
    esc[i] = expf(d0 * 0.0625f);
    s1[i] = d1;
    s2[i] = d2;
  }
}

// ---------------- column softmax stats for A ----------------
__global__ __launch_bounds__(256) void colstats_k(
    const float* __restrict__ H, const float* __restrict__ esc,
    float* __restrict__ colden, float* __restrict__ cnt)
{
  int e = blockIdx.x * 256 + threadIdx.x;
  int r0 = blockIdx.y * 128;
  float d = 0.f, c = 0.f;
  for (int r = r0; r < r0 + 128; ++r) {
    float h = H[(long)r * Ee + e];
    if (h > 0.f) { d += esc[r]; c += 1.f; }
  }
  atomicAdd(&colden[e], d);
  atomicAdd(&cnt[e], c);
}

// ---------------- A fill (tile): CAT A-half bf16 + AbT bf16 ----------------
__global__ __launch_bounds__(256) void fillA_k(
    const float* __restrict__ H, const float* __restrict__ esc,
    const float* __restrict__ colden,
    unsigned short* __restrict__ CAT, unsigned short* __restrict__ AbT)
{
  __shared__ unsigned short tile[64][68];
  int r0 = blockIdx.x * 64, e0 = blockIdx.y * 64;
  int te = threadIdx.x & 63, tq = threadIdx.x >> 6;
  float cd = colden[e0 + te];
  for (int rr = tq; rr < 64; rr += 4) {
    long idx = (long)(r0 + rr) * Ee + e0 + te;
    float h = H[idx];
    float val = h > 0.f ? esc[r0 + rr] / cd : 0.f;
    unsigned short vb = f2bf(val);
    CAT[(long)(r0 + rr) * 2048 + 1024 + e0 + te] = vb;
    tile[te][rr] = vb;
  }
  __syncthreads();
  for (int ee = tq; ee < 64; ee += 4)
    AbT[(long)(e0 + ee) * Nn + r0 + te] = tile[ee][te];
}

// ---------------- B row softmax: CAT B-half bf16 only ----------------
__global__ __launch_bounds__(256) void brow_k(const float* __restrict__ Bbuf,
                                              const float* __restrict__ H,
                                              unsigned short* __restrict__ CAT)
{
  int i = blockIdx.x, t = threadIdx.x;
  long base = (long)i * Ee + t * 4;
  float4 raw = *reinterpret_cast<const float4*>(&Bbuf[base]);
  float4 h = *reinterpret_cast<const float4*>(&H[base]);
  float rr[4] = {raw.x, raw.y, raw.z, raw.w}, hh[4] = {h.x, h.y, h.z, h.w};
  float p[4]; float s = 0.f;
  #pragma unroll
  for (int k = 0; k < 4; ++k) { p[k] = hh[k] > 0.f ? expf(rr[k]) : 0.f; s += p[k]; }
  float den = block_reduce_sum(s);
  float inv = den > 0.f ? 1.f / den : 0.f;
  ushort4 ob = {f2bf(p[0] * inv), f2bf(p[1] * inv), f2bf(p[2] * inv), f2bf(p[3] * inv)};
  *reinterpret_cast<ushort4*>(&CAT[(long)i * 2048 + t * 4]) = ob;
}

// ---------------- G fill: bf16 logits only ----------------
__global__ __launch_bounds__(256) void gfill_k(
    const float* __restrict__ adj, const float* __restrict__ s1,
    const float* __restrict__ s2, unsigned short* __restrict__ Gb)
{
  int i = blockIdx.x, t = threadIdx.x;
  float s1i = s1[i];
  float p[16]; float sum = 0.f;
  #pragma unroll
  for (int c = 0; c < 4; ++c) {
    int j = c * 1024 + t * 4;
    float4 a = *reinterpret_cast<const float4*>(&adj[(long)i * Nn + j]);
    float4 sv = *reinterpret_cast<const float4*>(&s2[j]);
    float aa[4] = {a.x, a.y, a.z, a.w}, ss[4] = {sv.x, sv.y, sv.z, sv.w};
    #pragma unroll
    for (int k = 0; k < 4; ++k) {
      float f = (aa[k] > 0.f ? 1.f : 0.f) + ((j + k) == i ? 1.f : 0.f);
      float l = s1i + ss[k];
      l = l > 0.f ? l : 0.2f * l;
      float val = l * f - 1e9f * fmaxf(1.f - f, 0.f);
      float pp = expf(val);
      p[c * 4 + k] = pp; sum += pp;
    }
  }
  float den = block_reduce_sum(sum);
  float inv = 1.f / den;
  #pragma unroll
  for (int c = 0; c < 4; ++c) {
    int j = c * 1024 + t * 4;
    ushort4 ob = {f2bf(p[c * 4] * inv), f2bf(p[c * 4 + 1] * inv),
                  f2bf(p[c * 4 + 2] * inv), f2bf(p[c * 4 + 3] * inv)};
    *reinterpret_cast<ushort4*>(&Gb[(long)i * Nn + j]) = ob;
  }
}

// ---------------- A_hat denominators (A from CAT bf16) ----------------
__global__ __launch_bounds__(256) void amstats_k(
    const unsigned short* __restrict__ CAT, const float* __restrict__ Mm,
    float* __restrict__ aden)
{
  int e = blockIdx.x * 256 + threadIdx.x;
  int r0 = blockIdx.y * 128;
  float d = 0.f;
  for (int r = r0; r < r0 + 128; ++r)
    d += expf(bf2f(CAT[(size_t)r * 2048 + 1024 + e]) + Mm[(size_t)r * Ee + e]);
  atomicAdd(&aden[e], d);
}

// ---------------- A_hat fill (A from CAT bf16, transpose, bf16 out) ----------------
__global__ __launch_bounds__(256) void ahat_k(
    const unsigned short* __restrict__ CAT, const float* __restrict__ Mm,
    const float* __restrict__ H, const float* __restrict__ aden,
    unsigned short* __restrict__ AhB)
{
  __shared__ float tile[64][65];
  int j0 = blockIdx.x * 64, e0 = blockIdx.y * 64;
  int te = threadIdx.x & 63;
  int tq = threadIdx.x >> 6;
  int e = e0 + te;
  float inv = 1.f / aden[e];
  for (int jj = tq; jj < 64; jj += 4) {
    long idx = (long)(j0 + jj) * Ee + e;
    float a = bf2f(CAT[(size_t)(j0 + jj) * 2048 + 1024 + e]);
    float val = (H[idx] > 0.f) ? expf(a + Mm[idx]) * inv : 0.f;
    tile[te][jj] = val;
  }
  __syncthreads();
  for (int ee = tq; ee < 64; ee += 4)
    AhB[(long)(e0 + ee) * Nn + j0 + te] = f2bf(tile[ee][te]);
}

// ---------------- B_hat (B from CAT bf16): bf16 out ----------------
__global__ __launch_bounds__(256) void bhat_k(const unsigned short* __restrict__ CAT,
                                              const float* __restrict__ Mm,
                                              const float* __restrict__ H,
                                              unsigned short* __restrict__ Bb2)
{
  int i = blockIdx.x, t = threadIdx.x;
  long base = (long)i * Ee + t * 4;
  ushort4 bu = *reinterpret_cast<const ushort4*>(&CAT[(long)i * 2048 + t * 4]);
  float4 m = *reinterpret_cast<const float4*>(&Mm[base]);
  float4 h = *reinterpret_cast<const float4*>(&H[base]);
  float bb[4] = {bf2f(bu.x), bf2f(bu.y), bf2f(bu.z), bf2f(bu.w)};
  float mm2[4] = {m.x, m.y, m.z, m.w}, hh[4] = {h.x, h.y, h.z, h.w};
  float p[4]; float s = 0.f;
  #pragma unroll
  for (int k = 0; k < 4; ++k) { p[k] = expf(bb[k] + mm2[k]); s += p[k]; }
  float den = block_reduce_sum(s);
  float inv = 1.f / den;
  #pragma unroll
  for (int k = 0; k < 4; ++k) p[k] = hh[k] > 0.f ? p[k] * inv : 0.f;
  ushort4 ob = {f2bf(p[0]), f2bf(p[1]), f2bf(p[2]), f2bf(p[3])};
  *reinterpret_cast<ushort4*>(&Bb2[base]) = ob;
}

// ---------------- launcher ----------------
extern "C" void kernel_launch(void* const* d_in, const int* in_sizes, int n_in,
                              void* d_out, int out_size, void* d_ws, size_t ws_size,
                              hipStream_t stream) {
  const float* x    = (const float*)d_in[0];
  const float* H    = (const float*)d_in[1];
  const float* adj  = (const float*)d_in[2];
  const float* W_he = (const float*)d_in[3];
  const float* u    = (const float*)d_in[4];
  const float* W_e  = (const float*)d_in[5];
  const float* W_n  = (const float*)d_in[6];
  const float* W_g  = (const float*)d_in[7];
  const float* a_g  = (const float*)d_in[8];
  float* out = (float*)d_out;
  float* ws  = (float*)d_ws;
  (void)in_sizes; (void)n_in; (void)out_size; (void)ws_size;

  size_t off = 0;
  auto alloc = [&](size_t n) { float* p = ws + off; off += n; return p; };
  float* hcat4  = alloc((size_t)Nn * 1024);  // [h_he | hn | h_g | hW]
  float* Wp     = alloc((size_t)Dd * Dd);    // W_he @ W_e
  float* esc    = alloc(Nn);
  float* s1     = alloc(Nn);
  float* s2     = alloc(Nn);
  float* colden = alloc(Ee);   // colden,cnt,aden,rowsum contiguous -> one memset
  float* cnt    = alloc(Ee);
  float* aden   = alloc(Ee);
  float* rowsum = alloc(Nn);
  float* heb    = alloc((size_t)Ee * Dd);    // heb,tewTf contiguous -> one memset
  float* tewTf  = alloc((size_t)Dd * Ee);
  float* Bbuf   = alloc((size_t)Nn * Ee);
  float* Mm     = alloc((size_t)Nn * Ee);
  unsigned short* Gb    = (unsigned short*)alloc((size_t)Nn * Nn / 2);
  unsigned short* CAT   = (unsigned short*)alloc((size_t)Nn * 2048 / 2);
  unsigned short* Hbt   = (unsigned short*)alloc((size_t)Ee * Nn / 2);
  unsigned short* AbT   = (unsigned short*)alloc((size_t)Ee * Nn / 2);
  unsigned short* AhB   = (unsigned short*)alloc((size_t)Ee * Nn / 2);
  unsigned short* hWT   = (unsigned short*)alloc((size_t)Dd * Nn / 2);
  unsigned short* hgT   = (unsigned short*)alloc((size_t)Dd * Nn / 2);
  unsigned short* tewT  = (unsigned short*)alloc((size_t)Dd * Ee / 2);
  unsigned short* Bb2   = (unsigned short*)alloc((size_t)Nn * Ee / 2);
  unsigned short* xb    = (unsigned short*)alloc((size_t)Nn * Dd / 2);
  unsigned short* WcTb4 = (unsigned short*)alloc((size_t)1024 * Dd / 2);
  unsigned short* hcatB = (unsigned short*)alloc((size_t)Nn * 1024 / 2);
  unsigned short* hebB  = (unsigned short*)alloc((size_t)Ee * Dd / 2);

  hipMemsetAsync(colden, 0, (3 * Ee + Nn) * sizeof(float), stream);
  hipMemsetAsync(heb, 0, 2 * (size_t)Ee * Dd * sizeof(float), stream);
  hipMemsetAsync(Mm, 0, (size_t)Nn * Ee * sizeof(float), stream);
  hipMemsetAsync(out, 0, 2 * (size_t)Nn * Dd * sizeof(float), stream);

  auto gbt = [&](const unsigned short* A, const unsigned short* B, float* C, unsigned short* Cb,
                 int M, int N, int K, int lda, int ldb, float alpha) {
    gemm_bt_bf16<<<dim3(M / 128, N / 128), 256, 0, stream>>>(A, B, C, Cb, M, N, K, lda, ldb, alpha);
  };
  auto gbts = [&](const unsigned short* A, const unsigned short* B, float* C,
                  int M, int N, int K, int lda, int ldb, int KS) {
    gemm_bts_bf16<<<dim3(M / 128, N / 128, K / KS), 256, 0, stream>>>(A, B, C, M, N, K, lda, ldb, KS);
  };
  auto gs64 = [&](const unsigned short* A, const unsigned short* B, float* C,
                  int M, int N, int K, int KS) {
    gemm64s_bt_bf16<<<dim3(M / 64, N / 64, K / KS), 256, 0, stream>>>(A, B, C, M, N, K, KS);
  };
  auto tcvt = [&](const float* in, unsigned short* o, int R, int S, int cols, const float* cd) {
    tcvt_k<<<dim3(R / 64, cols / 64), 256, 0, stream>>>(in, o, R, S, cd);
  };

  // Wp = W_he @ W_e (tiny f32)
  gemm64_k<<<dim3(4, 4), 256, 0, stream>>>(W_he, W_e, Wp, Dd, Dd, Dd, Dd, 1, Dd, 1);
  // bf16 operands
  cvt_bf16_k<<<(Nn * Dd) / 2048, 256, 0, stream>>>(x, xb, (long)Nn * Dd);
  tcvtW_k<<<dim3(4, 4, 4), 256, 0, stream>>>(W_he, W_n, W_g, Wp, WcTb4);
  // fused projections: hcat4(+hcatB) = x @ [W_he|W_n|W_g|Wp]
  gbt(xb, WcTb4, hcat4, hcatB, Nn, 1024, Dd, Dd, Dd, 1.f);
  rowdots_k<<<Nn, 256, 0, stream>>>(hcat4, u, a_g, esc, s1, s2);
  // hWT + hgT in one launch
  tcvtH_k<<<dim3(Nn / 64, Dd / 64, 2), 256, 0, stream>>>(hcat4, hWT, hgT);
  // A column softmax
  colstats_k<<<dim3(Ee / 256, 32), 256, 0, stream>>>(H, esc, colden, cnt);
  fillA_k<<<dim3(Nn / 64, Ee / 64), 256, 0, stream>>>(H, esc, colden, CAT, AbT);
  // heb = A^T @ hW  (split-K, 512 blocks)
  gs64(AbT, hWT, heb, Ee, Dd, Nn, 512);
  cvt_bf16_k<<<(Ee * Dd) / 2048, 256, 0, stream>>>(heb, hebB, (long)Ee * Dd);
  // Bsc = (hn @ heb^T)/16, row softmax -> CAT B-half
  gbt(hcatB + 256, hebB, Bbuf, nullptr, Nn, Ee, Dd, 1024, Dd, 0.0625f);
  brow_k<<<Nn, 256, 0, stream>>>(Bbuf, H, CAT);
  // G softmax -> bf16 logits
  gfill_k<<<Nn, 256, 0, stream>>>(adj, s1, s2, Gb);
  // M = G @ (H/he_sz) : pre-scaled Hbt, split-K atomic
  tcvt(H, Hbt, Nn, Ee, Ee, cnt);
  gbts(Gb, Hbt, Mm, Nn, Ee, Nn, Nn, Nn, 2048);
  // symmetric fused Gram (BK=64 + XOR swizzle, early-exit grid): Gb = exp(Gb + BB^T + AA^T)
  gemm_gram_k<<<dim3(32, 32), 256, 0, stream>>>(CAT, Gb, rowsum);
  // A_hat
  amstats_k<<<dim3(Ee / 256, 32), 256, 0, stream>>>(CAT, Mm, aden);
  ahat_k<<<dim3(Nn / 64, Ee / 64), 256, 0, stream>>>(CAT, Mm, H, aden, AhB);
  // tewT = (A_hat @ hW)^T = hW^T @ A_hat^T  (split-K, 512 blocks)
  gs64(hWT, AhB, tewTf, Dd, Ee, Nn, 512);
  cvt_bf16_k<<<(Dd * Ee) / 2048, 256, 0, stream>>>(tewTf, tewT, (long)Dd * Ee);
  // B_hat, z_h
  bhat_k<<<Nn, 256, 0, stream>>>(CAT, Mm, H, Bb2);
  gs64(Bb2, tewT, out, Nn, Dd, Ee, 512);
  // z_g (unnormalized) on 128^2-tile split-K (512 blocks), then row-scale + elu
  gbts(Gb, hgT, out + (size_t)Nn * Dd, Nn, Dd, Nn, Nn, Nn, 512);
  elu_rows_k<<<(2 * Nn * Dd) / 1024, 256, 0, stream>>>(out, rowsum);
}